// Round 5
// baseline (2114.865 us; speedup 1.0000x reference)
//
#include <hip/hip_runtime.h>
#include <math.h>

#define C_DIM 64
#define N_B 2
#define SPATIAL (64*64*64)
#define PLANE_SZ (64*64)
#define EPSV 1e-5f

// ---------------- K1: per-channel sum & sumsq ----------------
__global__ __launch_bounds__(256) void k_stats(const float* __restrict__ x,
                                               float* __restrict__ wsf) {
    int c = blockIdx.x >> 4;
    int part = blockIdx.x & 15;
    int tid = threadIdx.x;
    const int per_part = SPATIAL / 16;  // 16384 floats
    float s = 0.f, sq = 0.f;
    for (int n = 0; n < N_B; ++n) {
        const float* base = x + ((size_t)(n * C_DIM + c)) * SPATIAL + (size_t)part * per_part;
        const float4* b4 = (const float4*)base;
        #pragma unroll
        for (int it = 0; it < 16; ++it) {
            float4 v = b4[it * 256 + tid];
            s  += v.x + v.y + v.z + v.w;
            sq += v.x*v.x + v.y*v.y + v.z*v.z + v.w*v.w;
        }
    }
    __shared__ float rs[256], rq[256];
    rs[tid] = s; rq[tid] = sq;
    __syncthreads();
    for (int off = 128; off > 0; off >>= 1) {
        if (tid < off) { rs[tid] += rs[tid+off]; rq[tid] += rq[tid+off]; }
        __syncthreads();
    }
    if (tid == 0) {
        atomicAdd(&wsf[c], rs[0]);
        atomicAdd(&wsf[64 + c], rq[0]);
    }
}

// ---------------- K1b: finalize scale/shift ----------------
__global__ void k_finalize(float* __restrict__ wsf,
                           const float* __restrict__ gamma,
                           const float* __restrict__ beta) {
    int c = threadIdx.x;
    float cnt = (float)(N_B * SPATIAL);
    float mean = wsf[c] / cnt;
    float var = wsf[64 + c] / cnt - mean * mean;
    float sc = gamma[c] * rsqrtf(var + EPSV);
    wsf[128 + c] = sc;
    wsf[192 + c] = beta[c] - mean * sc;
}

// ---------------- K2: fused normalize + depthwise 5x5x5 (pad 2) ----------------
#define K2D 12
#define K2H 12
#define K2W 36
__global__ __launch_bounds__(256) void k_conv5(const float* __restrict__ x,
                                               const float* __restrict__ w0,
                                               const float* __restrict__ b0,
                                               const float* __restrict__ wsf,
                                               float* __restrict__ attn0) {
    __shared__ float sh[K2D * K2H * K2W];
    __shared__ float wt[125];
    int tid = threadIdx.x;
    int tx = tid & 31;
    int ty = tid >> 5;
    int wtile = blockIdx.x;        // 0..1
    int dt = blockIdx.y & 7;       // 0..7
    int ht = blockIdx.y >> 3;      // 0..7
    int nc = blockIdx.z;           // 0..127
    int c = nc & 63;
    int w0i = wtile * 32;
    int h0 = ht * 8;
    int d0 = dt * 8;
    const float* xb = x + (size_t)nc * SPATIAL;
    float sc = wsf[128 + c], shv = wsf[192 + c];
    if (tid < 125) wt[tid] = w0[c * 125 + tid];
    for (int idx = tid; idx < K2D * K2H * K2W; idx += 256) {
        int z = idx / (K2H * K2W);
        int rem = idx - z * (K2H * K2W);
        int y = rem / K2W;
        int xw = rem - y * K2W;
        int gd = d0 - 2 + z, gh = h0 - 2 + y, gw = w0i - 2 + xw;
        float v = 0.f;
        if ((unsigned)gd < 64u && (unsigned)gh < 64u && (unsigned)gw < 64u)
            v = xb[(size_t)gd * PLANE_SZ + gh * 64 + gw] * sc + shv;
        sh[idx] = v;
    }
    __syncthreads();
    float acc[8] = {0,0,0,0,0,0,0,0};
    #pragma unroll
    for (int z = 0; z < 12; ++z) {
        #pragma unroll
        for (int j = 0; j < 5; ++j) {
            #pragma unroll
            for (int k = 0; k < 5; ++k) {
                float v = sh[(z * K2H + (ty + j)) * K2W + tx + k];
                #pragma unroll
                for (int i = 0; i < 5; ++i) {
                    int dz = z - i;
                    if (dz >= 0 && dz < 8)
                        acc[dz] += wt[(i * 5 + j) * 5 + k] * v;
                }
            }
        }
    }
    float bias = b0[c];
    float* ob = attn0 + (size_t)nc * SPATIAL + (size_t)(h0 + ty) * 64 + w0i + tx;
    #pragma unroll
    for (int dz = 0; dz < 8; ++dz)
        ob[(size_t)(d0 + dz) * PLANE_SZ] = acc[dz] + bias;
}

// ---------------- K3 v7: dilated depthwise 7x7x7 via residue lattice ----------------
// The dilation-3 conv decomposes into independent residue sub-lattices in d and h.
// Block = one (rh, rd) residue pair for one nc; 384 threads = 64 w x 6 th.
// Each thread: 4 h-outputs (ah = 4*th+k) x ALL d-outputs via a 7-deep ring
// accumulator acc[4][7] (slot s at stage m <-> d-output j=m-3+s, d-tap t=6-s;
// slot 0 retires each stage, then shift -- all indices STATIC, runtime m-loop
// keeps code ~12 KB, I-cache safe). LDS stages only rows ≡ rh of plane
// z=3m+rd: each attn0 element staged EXACTLY once (no j0 overlap, no h-halo
// refetch). Per stage: 70 ds_read feed 1372 FMA (1:19.6, was 1:4 avg);
// one barrier per ~2850 cyc of work (was per ~750).
#define ROWS7 30                   /* row slots: a_tap = slot-3 in [-3,27) */
#define COLS7 84                   /* e = x+9 in [0,84) */
#define S7_T 384
#define S7_ITERS 7                 /* ceil(30*84/384) */
#define S7_BUF (S7_ITERS * S7_T)   /* 2688 floats per buffer */

__global__ __launch_bounds__(384, 4) void k_conv7(const float* __restrict__ attn0,
                                                  const float* __restrict__ wsv,
                                                  const float* __restrict__ bs,
                                                  float* __restrict__ attn1) {
    __shared__ float sh[2 * S7_BUF];   // 21 KB double buffer
    int tid = threadIdx.x;
    int w  = tid & 63;
    int th = tid >> 6;              // 0..5 (wave-uniform)
    int rh = blockIdx.x % 3;        // h residue
    int rd = blockIdx.x / 3;        // d residue (0..2)
    int nc = blockIdx.y;
    int c  = nc & 63;
    const float* ab = attn0 + (size_t)nc * SPATIAL;
    const float* wc = wsv + c * 343;    // block-uniform -> scalar loads
    int M = (66 - rd) / 3;          // #planes = #d-outputs (22,21,21)
    int ah0 = th * 4;
    int ahmax = (63 - rh) / 3;      // last valid h sub-lattice index

    // ---- hoisted staging geometry (identical every stage) ----
    int goff[S7_ITERS];
    float gmsk[S7_ITERS];
    #pragma unroll
    for (int kk = 0; kk < S7_ITERS; ++kk) {
        int idx = kk * S7_T + tid;
        int row = idx / COLS7;
        int e   = idx - row * COLS7;
        int gy  = 3 * (row - 3) + rh;
        int gx  = e - 9;
        bool valid = (row < ROWS7) && ((unsigned)gy < 64u) && ((unsigned)gx < 64u);
        goff[kk] = valid ? (gy * 64 + gx) : 0;   // clamped safe address
        gmsk[kk] = valid ? 1.f : 0.f;
    }

    float acc[4][7];
    #pragma unroll
    for (int k = 0; k < 4; ++k)
        #pragma unroll
        for (int s = 0; s < 7; ++s) acc[k][s] = 0.f;

    // ---- prologue: stage plane m=0 (z=rd) into buf0 ----
    {
        const float* pb = ab + (size_t)rd * PLANE_SZ;
        #pragma unroll
        for (int kk = 0; kk < S7_ITERS; ++kk)
            sh[kk * S7_T + tid] = pb[goff[kk]] * gmsk[kk];
    }
    __syncthreads();

    float bias = bs[c];
    // store cursor: first retire (m=3) is j=0 -> d=rd
    float* ob = attn1 + (size_t)nc * SPATIAL + (size_t)rd * PLANE_SZ
              + (size_t)(3 * ah0 + rh) * 64 + w;
    int rbase = ah0 * COLS7 + w;    // thread's row-block base within tile

    for (int m = 0; m < M; ++m) {
        const float* cur = sh + (m & 1) * S7_BUF;
        float* nxt = sh + ((m + 1) & 1) * S7_BUF;
        bool more = (m + 1 < M);    // block-uniform
        float r[S7_ITERS];
        if (more) {                 // issue next plane's loads FIRST (no wait)
            const float* pb = ab + (size_t)(3 * (m + 1) + rd) * PLANE_SZ;
            #pragma unroll
            for (int kk = 0; kk < S7_ITERS; ++kk)
                r[kk] = pb[goff[kk]];
        }
        // ---- compute stage m: 70 ds_read -> 1372 FMA, all-static indices ----
        #pragma unroll
        for (int jp = 0; jp < 10; ++jp) {
            float val[7];
            #pragma unroll
            for (int u = 0; u < 7; ++u)
                val[u] = cur[rbase + jp * COLS7 + 3 * u];
            #pragma unroll
            for (int k = 0; k < 4; ++k) {
                const int v = jp - k;            // compile-time after unroll
                if (v >= 0 && v < 7) {
                    #pragma unroll
                    for (int s = 0; s < 7; ++s) {
                        #pragma unroll
                        for (int u = 0; u < 7; ++u)
                            acc[k][s] = fmaf(wc[(6 - s) * 49 + v * 7 + u],
                                             val[u], acc[k][s]);
                    }
                }
            }
        }
        // ---- retire d-output j = m-3 from slot 0 ----
        if (m >= 3) {
            #pragma unroll
            for (int k = 0; k < 4; ++k)
                if (ah0 + k <= ahmax)
                    ob[k * 192] = acc[k][0] + bias;   // 192 = 3 rows * 64
            ob += 3 * PLANE_SZ;
        }
        if (more) {                 // drain loads, stage into other buffer
            #pragma unroll
            for (int kk = 0; kk < S7_ITERS; ++kk)
                nxt[kk * S7_T + tid] = r[kk] * gmsk[kk];
        }
        __syncthreads();
        // ---- shift ring (static) ----
        #pragma unroll
        for (int k = 0; k < 4; ++k) {
            #pragma unroll
            for (int s = 0; s < 6; ++s) acc[k][s] = acc[k][s + 1];
            acc[k][6] = 0.f;
        }
    }
    // ---- epilogue: slots 0..2 hold j = M-3..M-1 (all valid: Jd == M) ----
    #pragma unroll
    for (int s2 = 0; s2 < 3; ++s2) {
        #pragma unroll
        for (int k = 0; k < 4; ++k)
            if (ah0 + k <= ahmax)
                ob[k * 192] = acc[k][s2] + bias;
        ob += 3 * PLANE_SZ;
    }
}

// ---------------- K4: pointwise 1x1x1 (64->64) + bias + gate by x ----------------
__global__ __launch_bounds__(256) void k_pointwise(const float* __restrict__ attn1,
                                                   const float* __restrict__ x,
                                                   const float* __restrict__ w1,
                                                   const float* __restrict__ b1,
                                                   float* __restrict__ out) {
    __shared__ float at[64 * 64];
    int tid = threadIdx.x;
    int sl = tid & 63;
    int cg = __builtin_amdgcn_readfirstlane(tid >> 6);  // 0..3, wave-uniform
    int s0 = blockIdx.x * 64;
    int n = blockIdx.y;
    const float* a_base = attn1 + (size_t)n * C_DIM * SPATIAL + s0;
    #pragma unroll
    for (int it = 0; it < 16; ++it) {
        int idx = it * 256 + tid;
        int row = idx >> 6;
        at[idx] = a_base[(size_t)row * SPATIAL + sl];
    }
    __syncthreads();
    float acc[16];
    #pragma unroll
    for (int j = 0; j < 16; ++j) acc[j] = 0.f;
    for (int ci = 0; ci < 64; ++ci) {
        float va = at[ci * 64 + sl];
        #pragma unroll
        for (int j = 0; j < 16; ++j) {
            int cc = cg * 16 + j;
            acc[j] += w1[cc * 64 + ci] * va;   // wave-uniform -> scalar loads
        }
    }
    const float* xb = x + (size_t)n * C_DIM * SPATIAL + s0;
    float* ob = out + (size_t)n * C_DIM * SPATIAL + s0;
    #pragma unroll
    for (int j = 0; j < 16; ++j) {
        int cc = cg * 16 + j;
        float attn = acc[j] + b1[cc];
        ob[(size_t)cc * SPATIAL + sl] = xb[(size_t)cc * SPATIAL + sl] * attn;
    }
}

extern "C" void kernel_launch(void* const* d_in, const int* in_sizes, int n_in,
                              void* d_out, int out_size, void* d_ws, size_t ws_size,
                              hipStream_t stream) {
    const float* x     = (const float*)d_in[0];
    const float* gamma = (const float*)d_in[1];
    const float* beta  = (const float*)d_in[2];
    const float* w0    = (const float*)d_in[3];
    const float* b0    = (const float*)d_in[4];
    const float* wsv   = (const float*)d_in[5];
    const float* bs    = (const float*)d_in[6];
    const float* w1    = (const float*)d_in[7];
    const float* b1    = (const float*)d_in[8];
    float* out = (float*)d_out;
    float* wsf = (float*)d_ws;
    float* attn1 = wsf + 256;   // 134 MB intermediate in workspace

    hipMemsetAsync(d_ws, 0, 1024, stream);
    k_stats<<<dim3(1024), dim3(256), 0, stream>>>(x, wsf);
    k_finalize<<<dim3(1), dim3(64), 0, stream>>>(wsf, gamma, beta);
    // attn0 lives in d_out; overwritten later by K4 (stream-ordered, safe)
    k_conv5<<<dim3(2, 64, 128), dim3(256), 0, stream>>>(x, w0, b0, wsf, out);
    k_conv7<<<dim3(9, 128), dim3(384), 0, stream>>>(out, wsv, bs, attn1);
    k_pointwise<<<dim3(4096, 2), dim3(256), 0, stream>>>(attn1, x, w1, b1, out);
}

// Round 7
// 1820.424 us; speedup vs baseline: 1.1617x; 1.1617x over previous
//
#include <hip/hip_runtime.h>
#include <math.h>

#define C_DIM 64
#define N_B 2
#define SPATIAL (64*64*64)
#define PLANE_SZ (64*64)
#define EPSV 1e-5f

// ---------------- K1: per-channel sum & sumsq ----------------
__global__ __launch_bounds__(256) void k_stats(const float* __restrict__ x,
                                               float* __restrict__ wsf) {
    int c = blockIdx.x >> 4;
    int part = blockIdx.x & 15;
    int tid = threadIdx.x;
    const int per_part = SPATIAL / 16;  // 16384 floats
    float s = 0.f, sq = 0.f;
    for (int n = 0; n < N_B; ++n) {
        const float* base = x + ((size_t)(n * C_DIM + c)) * SPATIAL + (size_t)part * per_part;
        const float4* b4 = (const float4*)base;
        #pragma unroll
        for (int it = 0; it < 16; ++it) {
            float4 v = b4[it * 256 + tid];
            s  += v.x + v.y + v.z + v.w;
            sq += v.x*v.x + v.y*v.y + v.z*v.z + v.w*v.w;
        }
    }
    __shared__ float rs[256], rq[256];
    rs[tid] = s; rq[tid] = sq;
    __syncthreads();
    for (int off = 128; off > 0; off >>= 1) {
        if (tid < off) { rs[tid] += rs[tid+off]; rq[tid] += rq[tid+off]; }
        __syncthreads();
    }
    if (tid == 0) {
        atomicAdd(&wsf[c], rs[0]);
        atomicAdd(&wsf[64 + c], rq[0]);
    }
}

// ---------------- K1b: finalize scale/shift ----------------
__global__ void k_finalize(float* __restrict__ wsf,
                           const float* __restrict__ gamma,
                           const float* __restrict__ beta) {
    int c = threadIdx.x;
    float cnt = (float)(N_B * SPATIAL);
    float mean = wsf[c] / cnt;
    float var = wsf[64 + c] / cnt - mean * mean;
    float sc = gamma[c] * rsqrtf(var + EPSV);
    wsf[128 + c] = sc;
    wsf[192 + c] = beta[c] - mean * sc;
}

// ---------------- K2: fused normalize + depthwise 5x5x5 (pad 2) ----------------
#define K2D 12
#define K2H 12
#define K2W 36
__global__ __launch_bounds__(256) void k_conv5(const float* __restrict__ x,
                                               const float* __restrict__ w0,
                                               const float* __restrict__ b0,
                                               const float* __restrict__ wsf,
                                               float* __restrict__ attn0) {
    __shared__ float sh[K2D * K2H * K2W];
    __shared__ float wt[125];
    int tid = threadIdx.x;
    int tx = tid & 31;
    int ty = tid >> 5;
    int wtile = blockIdx.x;        // 0..1
    int dt = blockIdx.y & 7;       // 0..7
    int ht = blockIdx.y >> 3;      // 0..7
    int nc = blockIdx.z;           // 0..127
    int c = nc & 63;
    int w0i = wtile * 32;
    int h0 = ht * 8;
    int d0 = dt * 8;
    const float* xb = x + (size_t)nc * SPATIAL;
    float sc = wsf[128 + c], shv = wsf[192 + c];
    if (tid < 125) wt[tid] = w0[c * 125 + tid];
    for (int idx = tid; idx < K2D * K2H * K2W; idx += 256) {
        int z = idx / (K2H * K2W);
        int rem = idx - z * (K2H * K2W);
        int y = rem / K2W;
        int xw = rem - y * K2W;
        int gd = d0 - 2 + z, gh = h0 - 2 + y, gw = w0i - 2 + xw;
        float v = 0.f;
        if ((unsigned)gd < 64u && (unsigned)gh < 64u && (unsigned)gw < 64u)
            v = xb[(size_t)gd * PLANE_SZ + gh * 64 + gw] * sc + shv;
        sh[idx] = v;
    }
    __syncthreads();
    float acc[8] = {0,0,0,0,0,0,0,0};
    #pragma unroll
    for (int z = 0; z < 12; ++z) {
        #pragma unroll
        for (int j = 0; j < 5; ++j) {
            #pragma unroll
            for (int k = 0; k < 5; ++k) {
                float v = sh[(z * K2H + (ty + j)) * K2W + tx + k];
                #pragma unroll
                for (int i = 0; i < 5; ++i) {
                    int dz = z - i;
                    if (dz >= 0 && dz < 8)
                        acc[dz] += wt[(i * 5 + j) * 5 + k] * v;
                }
            }
        }
    }
    float bias = b0[c];
    float* ob = attn0 + (size_t)nc * SPATIAL + (size_t)(h0 + ty) * 64 + w0i + tx;
    #pragma unroll
    for (int dz = 0; dz < 8; ++dz)
        ob[(size_t)(d0 + dz) * PLANE_SZ] = acc[dz] + bias;
}

// ---------------- K3 v8: dilated depthwise 7x7x7, dil=3, pad 9 ----------------
// v6 template (straight-line stages, compile-time weight indices -> s_loads,
// hoisted goff/gmsk, LDS double-buffer, one barrier/stage) with the three
// j0-groups MERGED: acc[22] covers every d-output of this rd residue, 22
// straight-line plane-stages (plane P -> z=3P+rd). Plane P feeds outputs
// j = P-3+s (s,j compile-time) with weight slice t = 6-s. vs v6 per (ht,rd):
// stages 42->22, barriers -48%, ds_read 1372->1078, each attn0 element
// staged exactly once. R5 lesson honored: NO runtime loop around FMA bodies
// (v7's runtime m-loop broke weight scalarization -> per-lane loads + spills,
// 705us VALU busy). acc stays statically indexed.
#define ROWS7 26   /* 8 output rows + 18 halo */
#define COLS7 84   /* 82 valid + 2 pad */
#define S7_ELEMS (ROWS7 * COLS7)   /* 2184 */
#define S7_ITERS 5                 /* ceil(2184/512) */
#define S7_BUF 2560                /* per-buffer floats (incl. scribble pad) */
#define NJ7 22                     /* d-outputs per residue (<=22) */

template<int P>
__device__ __forceinline__ void conv7_stage(const float* __restrict__ ab,
                                            const float* __restrict__ wc,
                                            float* __restrict__ sh,
                                            int tid, int hh, int w, int rd,
                                            const int (&goff)[S7_ITERS],
                                            const float (&gmsk)[S7_ITERS],
                                            float (&acc)[NJ7]) {
    float* cur = sh + (P & 1) * S7_BUF;
    float* nxt = sh + ((P + 1) & 1) * S7_BUF;
    int zP = 3 * P + rd;
    bool zokP = (zP < 64);                       // block-uniform
    bool zokN = (P < 21) && (zP + 3 < 64);       // block-uniform

    float r[S7_ITERS];
    if (zokN) {                       // issue prefetch loads FIRST (no wait)
        const float* pb = ab + (size_t)(zP + 3) * PLANE_SZ;
        #pragma unroll
        for (int k = 0; k < S7_ITERS; ++k)
            r[k] = pb[goff[k]];
    }
    if (zokP) {                       // compute current plane (hides latency)
        #pragma unroll
        for (int v = 0; v < 7; ++v) {
            float val[7];
            int rb = (hh + 3 * v) * COLS7 + w;
            #pragma unroll
            for (int u = 0; u < 7; ++u) val[u] = cur[rb + 3 * u];
            #pragma unroll
            for (int s = 0; s < 7; ++s) {
                const int j = P - 3 + s;           // compile-time
                if (j >= 0 && j < NJ7) {
                    #pragma unroll
                    for (int u = 0; u < 7; ++u)
                        acc[j] = fmaf(wc[(6 - s) * 49 + v * 7 + u],
                                      val[u], acc[j]);
                }
            }
        }
    }
    if (zokN) {                       // drain loads, stage into other buffer
        #pragma unroll
        for (int k = 0; k < S7_ITERS; ++k)
            nxt[k * 512 + tid] = r[k] * gmsk[k];
    }
    __syncthreads();
}

__global__ __launch_bounds__(512, 4) void k_conv7(const float* __restrict__ attn0,
                                                  const float* __restrict__ wsv,
                                                  const float* __restrict__ bs,
                                                  float* __restrict__ attn1) {
    __shared__ float sh[2 * S7_BUF];   // 20 KB double buffer
    int tid = threadIdx.x;
    int w = tid & 63;
    int hh = tid >> 6;             // 0..7  (wave-uniform)
    int ht = blockIdx.x;           // 0..7
    int rd = blockIdx.y;           // d residue 0..2
    int nc = blockIdx.z;
    int c = nc & 63;
    int h0 = ht * 8;
    int h = h0 + hh;
    const float* ab = attn0 + (size_t)nc * SPATIAL;
    const float* wc = wsv + c * 343;   // block-uniform -> scalar loads

    // ---- hoisted staging geometry: identical for every stage ----
    int goff[S7_ITERS];
    float gmsk[S7_ITERS];
    #pragma unroll
    for (int k = 0; k < S7_ITERS; ++k) {
        int idx = k * 512 + tid;
        int row = idx / COLS7;
        int col = idx - row * COLS7;
        int gy = h0 - 9 + row;
        int gx = col - 9;
        bool valid = (idx < S7_ELEMS) && (col < 82) &&
                     ((unsigned)gy < 64u) && ((unsigned)gx < 64u);
        goff[k] = valid ? (gy * 64 + gx) : 0;   // clamped to a safe address
        gmsk[k] = valid ? 1.f : 0.f;
    }

    // ---- prologue: stage plane P=0 (z=rd, always valid) into buf0 ----
    {
        const float* pb = ab + (size_t)rd * PLANE_SZ;
        #pragma unroll
        for (int k = 0; k < S7_ITERS; ++k)
            sh[k * 512 + tid] = pb[goff[k]] * gmsk[k];
    }
    __syncthreads();

    float acc[NJ7];
    #pragma unroll
    for (int j = 0; j < NJ7; ++j) acc[j] = 0.f;

    conv7_stage< 0>(ab, wc, sh, tid, hh, w, rd, goff, gmsk, acc);
    conv7_stage< 1>(ab, wc, sh, tid, hh, w, rd, goff, gmsk, acc);
    conv7_stage< 2>(ab, wc, sh, tid, hh, w, rd, goff, gmsk, acc);
    conv7_stage< 3>(ab, wc, sh, tid, hh, w, rd, goff, gmsk, acc);
    conv7_stage< 4>(ab, wc, sh, tid, hh, w, rd, goff, gmsk, acc);
    conv7_stage< 5>(ab, wc, sh, tid, hh, w, rd, goff, gmsk, acc);
    conv7_stage< 6>(ab, wc, sh, tid, hh, w, rd, goff, gmsk, acc);
    conv7_stage< 7>(ab, wc, sh, tid, hh, w, rd, goff, gmsk, acc);
    conv7_stage< 8>(ab, wc, sh, tid, hh, w, rd, goff, gmsk, acc);
    conv7_stage< 9>(ab, wc, sh, tid, hh, w, rd, goff, gmsk, acc);
    conv7_stage<10>(ab, wc, sh, tid, hh, w, rd, goff, gmsk, acc);
    conv7_stage<11>(ab, wc, sh, tid, hh, w, rd, goff, gmsk, acc);
    conv7_stage<12>(ab, wc, sh, tid, hh, w, rd, goff, gmsk, acc);
    conv7_stage<13>(ab, wc, sh, tid, hh, w, rd, goff, gmsk, acc);
    conv7_stage<14>(ab, wc, sh, tid, hh, w, rd, goff, gmsk, acc);
    conv7_stage<15>(ab, wc, sh, tid, hh, w, rd, goff, gmsk, acc);
    conv7_stage<16>(ab, wc, sh, tid, hh, w, rd, goff, gmsk, acc);
    conv7_stage<17>(ab, wc, sh, tid, hh, w, rd, goff, gmsk, acc);
    conv7_stage<18>(ab, wc, sh, tid, hh, w, rd, goff, gmsk, acc);
    conv7_stage<19>(ab, wc, sh, tid, hh, w, rd, goff, gmsk, acc);
    conv7_stage<20>(ab, wc, sh, tid, hh, w, rd, goff, gmsk, acc);
    conv7_stage<21>(ab, wc, sh, tid, hh, w, rd, goff, gmsk, acc);

    float bias = bs[c];
    float* ob = attn1 + (size_t)nc * SPATIAL + (size_t)h * 64 + w;
    #pragma unroll
    for (int j = 0; j < NJ7; ++j) {
        int d = 3 * j + rd;
        if (d < 64)
            ob[(size_t)d * PLANE_SZ] = acc[j] + bias;
    }
}

// ---------------- K4: pointwise 1x1x1 (64->64) + bias + gate by x ----------------
__global__ __launch_bounds__(256) void k_pointwise(const float* __restrict__ attn1,
                                                   const float* __restrict__ x,
                                                   const float* __restrict__ w1,
                                                   const float* __restrict__ b1,
                                                   float* __restrict__ out) {
    __shared__ float at[64 * 64];
    int tid = threadIdx.x;
    int sl = tid & 63;
    int cg = __builtin_amdgcn_readfirstlane(tid >> 6);  // 0..3, wave-uniform
    int s0 = blockIdx.x * 64;
    int n = blockIdx.y;
    const float* a_base = attn1 + (size_t)n * C_DIM * SPATIAL + s0;
    #pragma unroll
    for (int it = 0; it < 16; ++it) {
        int idx = it * 256 + tid;
        int row = idx >> 6;
        at[idx] = a_base[(size_t)row * SPATIAL + sl];
    }
    __syncthreads();
    float acc[16];
    #pragma unroll
    for (int j = 0; j < 16; ++j) acc[j] = 0.f;
    for (int ci = 0; ci < 64; ++ci) {
        float va = at[ci * 64 + sl];
        #pragma unroll
        for (int j = 0; j < 16; ++j) {
            int cc = cg * 16 + j;
            acc[j] += w1[cc * 64 + ci] * va;   // wave-uniform -> scalar loads
        }
    }
    const float* xb = x + (size_t)n * C_DIM * SPATIAL + s0;
    float* ob = out + (size_t)n * C_DIM * SPATIAL + s0;
    #pragma unroll
    for (int j = 0; j < 16; ++j) {
        int cc = cg * 16 + j;
        float attn = acc[j] + b1[cc];
        ob[(size_t)cc * SPATIAL + sl] = xb[(size_t)cc * SPATIAL + sl] * attn;
    }
}

extern "C" void kernel_launch(void* const* d_in, const int* in_sizes, int n_in,
                              void* d_out, int out_size, void* d_ws, size_t ws_size,
                              hipStream_t stream) {
    const float* x     = (const float*)d_in[0];
    const float* gamma = (const float*)d_in[1];
    const float* beta  = (const float*)d_in[2];
    const float* w0    = (const float*)d_in[3];
    const float* b0    = (const float*)d_in[4];
    const float* wsv   = (const float*)d_in[5];
    const float* bs    = (const float*)d_in[6];
    const float* w1    = (const float*)d_in[7];
    const float* b1    = (const float*)d_in[8];
    float* out = (float*)d_out;
    float* wsf = (float*)d_ws;
    float* attn1 = wsf + 256;   // 134 MB intermediate in workspace

    hipMemsetAsync(d_ws, 0, 1024, stream);
    k_stats<<<dim3(1024), dim3(256), 0, stream>>>(x, wsf);
    k_finalize<<<dim3(1), dim3(64), 0, stream>>>(wsf, gamma, beta);
    // attn0 lives in d_out; overwritten later by K4 (stream-ordered, safe)
    k_conv5<<<dim3(2, 64, 128), dim3(256), 0, stream>>>(x, w0, b0, wsf, out);
    k_conv7<<<dim3(8, 3, 128), dim3(512), 0, stream>>>(out, wsv, bs, attn1);
    k_pointwise<<<dim3(4096, 2), dim3(256), 0, stream>>>(attn1, x, w1, b1, out);
}

// Round 8
// 1142.622 us; speedup vs baseline: 1.8509x; 1.5932x over previous
//
#include <hip/hip_runtime.h>
#include <math.h>

#define C_DIM 64
#define N_B 2
#define SPATIAL (64*64*64)
#define PLANE_SZ (64*64)
#define EPSV 1e-5f

// ---------------- K1: per-channel sum & sumsq ----------------
__global__ __launch_bounds__(256) void k_stats(const float* __restrict__ x,
                                               float* __restrict__ wsf) {
    int c = blockIdx.x >> 4;
    int part = blockIdx.x & 15;
    int tid = threadIdx.x;
    const int per_part = SPATIAL / 16;  // 16384 floats
    float s = 0.f, sq = 0.f;
    for (int n = 0; n < N_B; ++n) {
        const float* base = x + ((size_t)(n * C_DIM + c)) * SPATIAL + (size_t)part * per_part;
        const float4* b4 = (const float4*)base;
        #pragma unroll
        for (int it = 0; it < 16; ++it) {
            float4 v = b4[it * 256 + tid];
            s  += v.x + v.y + v.z + v.w;
            sq += v.x*v.x + v.y*v.y + v.z*v.z + v.w*v.w;
        }
    }
    __shared__ float rs[256], rq[256];
    rs[tid] = s; rq[tid] = sq;
    __syncthreads();
    for (int off = 128; off > 0; off >>= 1) {
        if (tid < off) { rs[tid] += rs[tid+off]; rq[tid] += rq[tid+off]; }
        __syncthreads();
    }
    if (tid == 0) {
        atomicAdd(&wsf[c], rs[0]);
        atomicAdd(&wsf[64 + c], rq[0]);
    }
}

// ---------------- K1b: finalize scale/shift ----------------
__global__ void k_finalize(float* __restrict__ wsf,
                           const float* __restrict__ gamma,
                           const float* __restrict__ beta) {
    int c = threadIdx.x;
    float cnt = (float)(N_B * SPATIAL);
    float mean = wsf[c] / cnt;
    float var = wsf[64 + c] / cnt - mean * mean;
    float sc = gamma[c] * rsqrtf(var + EPSV);
    wsf[128 + c] = sc;
    wsf[192 + c] = beta[c] - mean * sc;
}

// ---------------- K2: fused normalize + depthwise 5x5x5 (pad 2) ----------------
// R7 change: weights were in LDS (wt[125]) -> EVERY weight access was a
// ds_read, ~1500 extra LDS-pipe issues per thread vs 1000 FMAs (LDS-bound).
// Now: block-uniform pointer + compile-time indices -> scalar s_loads
// (the proven conv7 pattern). LDS weight buffer deleted.
#define K2D 12
#define K2H 12
#define K2W 36
__global__ __launch_bounds__(256) void k_conv5(const float* __restrict__ x,
                                               const float* __restrict__ w0,
                                               const float* __restrict__ b0,
                                               const float* __restrict__ wsf,
                                               float* __restrict__ attn0) {
    __shared__ float sh[K2D * K2H * K2W];
    int tid = threadIdx.x;
    int tx = tid & 31;
    int ty = tid >> 5;
    int wtile = blockIdx.x;        // 0..1
    int dt = blockIdx.y & 7;       // 0..7
    int ht = blockIdx.y >> 3;      // 0..7
    int nc = blockIdx.z;           // 0..127
    int c = nc & 63;
    int w0i = wtile * 32;
    int h0 = ht * 8;
    int d0 = dt * 8;
    const float* xb = x + (size_t)nc * SPATIAL;
    const float* wcp = w0 + c * 125;   // block-uniform -> scalar loads
    float sc = wsf[128 + c], shv = wsf[192 + c];
    for (int idx = tid; idx < K2D * K2H * K2W; idx += 256) {
        int z = idx / (K2H * K2W);
        int rem = idx - z * (K2H * K2W);
        int y = rem / K2W;
        int xw = rem - y * K2W;
        int gd = d0 - 2 + z, gh = h0 - 2 + y, gw = w0i - 2 + xw;
        float v = 0.f;
        if ((unsigned)gd < 64u && (unsigned)gh < 64u && (unsigned)gw < 64u)
            v = xb[(size_t)gd * PLANE_SZ + gh * 64 + gw] * sc + shv;
        sh[idx] = v;
    }
    __syncthreads();
    float acc[8] = {0,0,0,0,0,0,0,0};
    #pragma unroll
    for (int z = 0; z < 12; ++z) {
        #pragma unroll
        for (int j = 0; j < 5; ++j) {
            #pragma unroll
            for (int k = 0; k < 5; ++k) {
                float v = sh[(z * K2H + (ty + j)) * K2W + tx + k];
                #pragma unroll
                for (int i = 0; i < 5; ++i) {
                    int dz = z - i;
                    if (dz >= 0 && dz < 8)
                        acc[dz] += wcp[(i * 5 + j) * 5 + k] * v;
                }
            }
        }
    }
    float bias = b0[c];
    float* ob = attn0 + (size_t)nc * SPATIAL + (size_t)(h0 + ty) * 64 + w0i + tx;
    #pragma unroll
    for (int dz = 0; dz < 8; ++dz)
        ob[(size_t)(d0 + dz) * PLANE_SZ] = acc[dz] + bias;
}

// ---------------- K3 v9: dilated depthwise 7x7x7, dil=3, pad 9 ----------------
// R7 post-mortem: v8's merged acc[22] body (~45+ KB straight-line) thrashed
// the ~32 KB I-cache (dur 2x, VALUBusy 63->29.5% with busy-TIME unchanged).
// Fix (pre-registered fallback): TWO-GROUP split, NJ=11, 14 stages per group,
// ~26 KB per kernel -> fits I-cache. Separate kernels g0/g1 so a CU never
// mixes both code paths. Keeps v8's gains vs v6: ds_read/output 62 (was 86),
// total barriers -33%. Same proven template: straight-line stages,
// compile-time weight indices -> s_loads, hoisted goff/gmsk, LDS dbuf,
// one barrier/stage. acc statically indexed. NO runtime loop around FMAs.
#define ROWS7 26   /* 8 output rows + 18 halo */
#define COLS7 84   /* 82 valid + 2 pad */
#define S7_ELEMS (ROWS7 * COLS7)   /* 2184 */
#define S7_ITERS 5                 /* ceil(2184/512) */
#define S7_BUF 2560                /* per-buffer floats (incl. scribble pad) */
#define NJ7 11                     /* d-outputs per group */

template<int P, int JB, int PLAST>
__device__ __forceinline__ void conv7_stage(const float* __restrict__ ab,
                                            const float* __restrict__ wc,
                                            float* __restrict__ sh,
                                            int tid, int hh, int w, int rd,
                                            const int (&goff)[S7_ITERS],
                                            const float (&gmsk)[S7_ITERS],
                                            float (&acc)[NJ7]) {
    float* cur = sh + (P & 1) * S7_BUF;
    float* nxt = sh + ((P + 1) & 1) * S7_BUF;
    int zP = 3 * P + rd;
    bool zokP = (zP < 64);                            // block-uniform
    bool zokN = (P < PLAST) && (zP + 3 < 64);         // block-uniform

    float r[S7_ITERS];
    if (zokN) {                       // issue prefetch loads FIRST (no wait)
        const float* pb = ab + (size_t)(zP + 3) * PLANE_SZ;
        #pragma unroll
        for (int k = 0; k < S7_ITERS; ++k)
            r[k] = pb[goff[k]];
    }
    if (zokP) {                       // compute current plane (hides latency)
        #pragma unroll
        for (int v = 0; v < 7; ++v) {
            float val[7];
            int rb = (hh + 3 * v) * COLS7 + w;
            #pragma unroll
            for (int u = 0; u < 7; ++u) val[u] = cur[rb + 3 * u];
            #pragma unroll
            for (int s = 0; s < 7; ++s) {
                const int j = P - 3 + s;           // compile-time
                if (j >= JB && j < JB + NJ7 && j < 22) {
                    #pragma unroll
                    for (int u = 0; u < 7; ++u)
                        acc[j - JB] = fmaf(wc[(6 - s) * 49 + v * 7 + u],
                                           val[u], acc[j - JB]);
                }
            }
        }
    }
    if (zokN) {                       // drain loads, stage into other buffer
        #pragma unroll
        for (int k = 0; k < S7_ITERS; ++k)
            nxt[k * 512 + tid] = r[k] * gmsk[k];
    }
    __syncthreads();
}

// common per-block setup
#define CONV7_PREAMBLE                                                      \
    __shared__ float sh[2 * S7_BUF];                                        \
    int tid = threadIdx.x;                                                  \
    int w = tid & 63;                                                       \
    int hh = tid >> 6;                                                      \
    int ht = blockIdx.x;                                                    \
    int rd = blockIdx.y;                                                    \
    int nc = blockIdx.z;                                                    \
    int c = nc & 63;                                                        \
    int h0 = ht * 8;                                                        \
    int h = h0 + hh;                                                        \
    const float* ab = attn0 + (size_t)nc * SPATIAL;                         \
    const float* wc = wsv + c * 343;                                        \
    int goff[S7_ITERS];                                                     \
    float gmsk[S7_ITERS];                                                   \
    _Pragma("unroll")                                                       \
    for (int k = 0; k < S7_ITERS; ++k) {                                    \
        int idx = k * 512 + tid;                                            \
        int row = idx / COLS7;                                              \
        int col = idx - row * COLS7;                                        \
        int gy = h0 - 9 + row;                                              \
        int gx = col - 9;                                                   \
        bool valid = (idx < S7_ELEMS) && (col < 82) &&                      \
                     ((unsigned)gy < 64u) && ((unsigned)gx < 64u);          \
        goff[k] = valid ? (gy * 64 + gx) : 0;                               \
        gmsk[k] = valid ? 1.f : 0.f;                                        \
    }                                                                       \
    float acc[NJ7];                                                         \
    _Pragma("unroll")                                                       \
    for (int j = 0; j < NJ7; ++j) acc[j] = 0.f;

#define CONV7_EPILOGUE(JB)                                                  \
    float bias = bs[c];                                                     \
    float* ob = attn1 + (size_t)nc * SPATIAL + (size_t)h * 64 + w;          \
    _Pragma("unroll")                                                       \
    for (int j = 0; j < NJ7; ++j) {                                         \
        int d = 3 * (JB + j) + rd;                                          \
        if (d < 64)                                                         \
            ob[(size_t)d * PLANE_SZ] = acc[j] + bias;                       \
    }

// Group 0: outputs j in [0,11), planes P = 0..13
__global__ __launch_bounds__(512, 4) void k_conv7_g0(const float* __restrict__ attn0,
                                                     const float* __restrict__ wsv,
                                                     const float* __restrict__ bs,
                                                     float* __restrict__ attn1) {
    CONV7_PREAMBLE
    {   // prologue: stage plane P=0 (z=rd, always valid) into buf0
        const float* pb = ab + (size_t)rd * PLANE_SZ;
        #pragma unroll
        for (int k = 0; k < S7_ITERS; ++k)
            sh[k * 512 + tid] = pb[goff[k]] * gmsk[k];
    }
    __syncthreads();
    conv7_stage< 0, 0, 13>(ab, wc, sh, tid, hh, w, rd, goff, gmsk, acc);
    conv7_stage< 1, 0, 13>(ab, wc, sh, tid, hh, w, rd, goff, gmsk, acc);
    conv7_stage< 2, 0, 13>(ab, wc, sh, tid, hh, w, rd, goff, gmsk, acc);
    conv7_stage< 3, 0, 13>(ab, wc, sh, tid, hh, w, rd, goff, gmsk, acc);
    conv7_stage< 4, 0, 13>(ab, wc, sh, tid, hh, w, rd, goff, gmsk, acc);
    conv7_stage< 5, 0, 13>(ab, wc, sh, tid, hh, w, rd, goff, gmsk, acc);
    conv7_stage< 6, 0, 13>(ab, wc, sh, tid, hh, w, rd, goff, gmsk, acc);
    conv7_stage< 7, 0, 13>(ab, wc, sh, tid, hh, w, rd, goff, gmsk, acc);
    conv7_stage< 8, 0, 13>(ab, wc, sh, tid, hh, w, rd, goff, gmsk, acc);
    conv7_stage< 9, 0, 13>(ab, wc, sh, tid, hh, w, rd, goff, gmsk, acc);
    conv7_stage<10, 0, 13>(ab, wc, sh, tid, hh, w, rd, goff, gmsk, acc);
    conv7_stage<11, 0, 13>(ab, wc, sh, tid, hh, w, rd, goff, gmsk, acc);
    conv7_stage<12, 0, 13>(ab, wc, sh, tid, hh, w, rd, goff, gmsk, acc);
    conv7_stage<13, 0, 13>(ab, wc, sh, tid, hh, w, rd, goff, gmsk, acc);
    CONV7_EPILOGUE(0)
}

// Group 1: outputs j in [11,22), planes P = 8..21
__global__ __launch_bounds__(512, 4) void k_conv7_g1(const float* __restrict__ attn0,
                                                     const float* __restrict__ wsv,
                                                     const float* __restrict__ bs,
                                                     float* __restrict__ attn1) {
    CONV7_PREAMBLE
    {   // prologue: stage plane P=8 (z=24+rd, always valid) into buf0 (8&1==0)
        const float* pb = ab + (size_t)(24 + rd) * PLANE_SZ;
        #pragma unroll
        for (int k = 0; k < S7_ITERS; ++k)
            sh[k * 512 + tid] = pb[goff[k]] * gmsk[k];
    }
    __syncthreads();
    conv7_stage< 8, 11, 21>(ab, wc, sh, tid, hh, w, rd, goff, gmsk, acc);
    conv7_stage< 9, 11, 21>(ab, wc, sh, tid, hh, w, rd, goff, gmsk, acc);
    conv7_stage<10, 11, 21>(ab, wc, sh, tid, hh, w, rd, goff, gmsk, acc);
    conv7_stage<11, 11, 21>(ab, wc, sh, tid, hh, w, rd, goff, gmsk, acc);
    conv7_stage<12, 11, 21>(ab, wc, sh, tid, hh, w, rd, goff, gmsk, acc);
    conv7_stage<13, 11, 21>(ab, wc, sh, tid, hh, w, rd, goff, gmsk, acc);
    conv7_stage<14, 11, 21>(ab, wc, sh, tid, hh, w, rd, goff, gmsk, acc);
    conv7_stage<15, 11, 21>(ab, wc, sh, tid, hh, w, rd, goff, gmsk, acc);
    conv7_stage<16, 11, 21>(ab, wc, sh, tid, hh, w, rd, goff, gmsk, acc);
    conv7_stage<17, 11, 21>(ab, wc, sh, tid, hh, w, rd, goff, gmsk, acc);
    conv7_stage<18, 11, 21>(ab, wc, sh, tid, hh, w, rd, goff, gmsk, acc);
    conv7_stage<19, 11, 21>(ab, wc, sh, tid, hh, w, rd, goff, gmsk, acc);
    conv7_stage<20, 11, 21>(ab, wc, sh, tid, hh, w, rd, goff, gmsk, acc);
    conv7_stage<21, 11, 21>(ab, wc, sh, tid, hh, w, rd, goff, gmsk, acc);
    CONV7_EPILOGUE(11)
}

// ---------------- K4: pointwise 1x1x1 (64->64) + bias + gate by x ----------------
__global__ __launch_bounds__(256) void k_pointwise(const float* __restrict__ attn1,
                                                   const float* __restrict__ x,
                                                   const float* __restrict__ w1,
                                                   const float* __restrict__ b1,
                                                   float* __restrict__ out) {
    __shared__ float at[64 * 64];
    int tid = threadIdx.x;
    int sl = tid & 63;
    int cg = __builtin_amdgcn_readfirstlane(tid >> 6);  // 0..3, wave-uniform
    int s0 = blockIdx.x * 64;
    int n = blockIdx.y;
    const float* a_base = attn1 + (size_t)n * C_DIM * SPATIAL + s0;
    #pragma unroll
    for (int it = 0; it < 16; ++it) {
        int idx = it * 256 + tid;
        int row = idx >> 6;
        at[idx] = a_base[(size_t)row * SPATIAL + sl];
    }
    __syncthreads();
    float acc[16];
    #pragma unroll
    for (int j = 0; j < 16; ++j) acc[j] = 0.f;
    for (int ci = 0; ci < 64; ++ci) {
        float va = at[ci * 64 + sl];
        #pragma unroll
        for (int j = 0; j < 16; ++j) {
            int cc = cg * 16 + j;
            acc[j] += w1[cc * 64 + ci] * va;   // wave-uniform -> scalar loads
        }
    }
    const float* xb = x + (size_t)n * C_DIM * SPATIAL + s0;
    float* ob = out + (size_t)n * C_DIM * SPATIAL + s0;
    #pragma unroll
    for (int j = 0; j < 16; ++j) {
        int cc = cg * 16 + j;
        float attn = acc[j] + b1[cc];
        ob[(size_t)cc * SPATIAL + sl] = xb[(size_t)cc * SPATIAL + sl] * attn;
    }
}

extern "C" void kernel_launch(void* const* d_in, const int* in_sizes, int n_in,
                              void* d_out, int out_size, void* d_ws, size_t ws_size,
                              hipStream_t stream) {
    const float* x     = (const float*)d_in[0];
    const float* gamma = (const float*)d_in[1];
    const float* beta  = (const float*)d_in[2];
    const float* w0    = (const float*)d_in[3];
    const float* b0    = (const float*)d_in[4];
    const float* wsv   = (const float*)d_in[5];
    const float* bs    = (const float*)d_in[6];
    const float* w1    = (const float*)d_in[7];
    const float* b1    = (const float*)d_in[8];
    float* out = (float*)d_out;
    float* wsf = (float*)d_ws;
    float* attn1 = wsf + 256;   // 134 MB intermediate in workspace

    hipMemsetAsync(d_ws, 0, 1024, stream);
    k_stats<<<dim3(1024), dim3(256), 0, stream>>>(x, wsf);
    k_finalize<<<dim3(1), dim3(64), 0, stream>>>(wsf, gamma, beta);
    // attn0 lives in d_out; overwritten later by K4 (stream-ordered, safe)
    k_conv5<<<dim3(2, 64, 128), dim3(256), 0, stream>>>(x, w0, b0, wsf, out);
    k_conv7_g0<<<dim3(8, 3, 128), dim3(512), 0, stream>>>(out, wsv, bs, attn1);
    k_conv7_g1<<<dim3(8, 3, 128), dim3(512), 0, stream>>>(out, wsv, bs, attn1);
    k_pointwise<<<dim3(4096, 2), dim3(256), 0, stream>>>(attn1, x, w1, b1, out);
}